// Round 13
// baseline (341.464 us; speedup 1.0000x reference)
//
#include <hip/hip_runtime.h>
#include <math.h>

#define BB 16
#define NN 8400
#define CC 80
#define MM 64
#define KTOP 13
#define FEPS 1e-9f
#define CAP 2048     // per-(b,m) candidate capacity; theoretical max 1344
#define RPW 8        // u64 regs/lane for selection: RPW*256 == CAP
#define NBLK 1024    // persistent grid: 4 blocks/CU, co-resident by construction
#define NT1 2112     // P1 tiles: 132 chunks x 16 batches
#define NT3 528      // P3 tiles: 33 chunks x 16 batches

typedef float floatx4 __attribute__((ext_vector_type(4)));
typedef unsigned long long u64;

// ---- output layout (floats) ----
#define OFF_O1 134400
#define OFF_O2 672000
#define OFF_O3 11424000
#define OFF_O4 11558400

// ---- d_ws layout (ints) ----
// bar[2] | ccnt[1024] | cntb[134400] | mselb[134400] | aselb[134400] | cand u64[1024*2048]
#define ZERO_INTS (2 + 1024 + 3 * 134400)   // memset-zeroed every launch

__device__ __forceinline__ float iou_pair(const float4 g, const float4 p) {
    float ix1 = fmaxf(g.x, p.x);
    float iy1 = fmaxf(g.y, p.y);
    float ix2 = fminf(g.z, p.z);
    float iy2 = fminf(g.w, p.w);
    float iw = fmaxf(ix2 - ix1, 0.0f);
    float ih = fmaxf(iy2 - iy1, 0.0f);
    float inter = iw * ih;
    float aa = (g.z - g.x) * (g.w - g.y);
    float ab = (p.z - p.x) * (p.w - p.y);
    float uni = fmaxf(aa + ab - inter, FEPS);
    return inter / uni;
}

// agent(device)-scope ops: bypass non-coherent per-XCD caches for cross-phase data
__device__ __forceinline__ void st_dev_u64(u64* p, u64 v) {
    __hip_atomic_store(p, v, __ATOMIC_RELAXED, __HIP_MEMORY_SCOPE_AGENT);
}
__device__ __forceinline__ u64 ld_dev_u64(const u64* p) {
    return __hip_atomic_load(p, __ATOMIC_RELAXED, __HIP_MEMORY_SCOPE_AGENT);
}
__device__ __forceinline__ int ld_dev_i32(const int* p) {
    return __hip_atomic_load(p, __ATOMIC_RELAXED, __HIP_MEMORY_SCOPE_AGENT);
}
__device__ __forceinline__ float ld_dev_f32(const float* p) {
    return __hip_atomic_load(p, __ATOMIC_RELAXED, __HIP_MEMORY_SCOPE_AGENT);
}

// generation-based grid barrier; all NBLK blocks are co-resident (4/CU).
__device__ void grid_barrier(int* bar) {
    __syncthreads();
    if (threadIdx.x == 0) {
        __threadfence();   // release my writes to device scope
        int g = __hip_atomic_load(&bar[1], __ATOMIC_RELAXED, __HIP_MEMORY_SCOPE_AGENT);
        int a = __hip_atomic_fetch_add(&bar[0], 1, __ATOMIC_ACQ_REL, __HIP_MEMORY_SCOPE_AGENT);
        if (a == NBLK - 1) {
            __hip_atomic_store(&bar[0], 0, __ATOMIC_RELAXED, __HIP_MEMORY_SCOPE_AGENT);
            __hip_atomic_fetch_add(&bar[1], 1, __ATOMIC_RELEASE, __HIP_MEMORY_SCOPE_AGENT);
        } else {
            while (__hip_atomic_load(&bar[1], __ATOMIC_ACQUIRE, __HIP_MEMORY_SCOPE_AGENT) == g)
                __builtin_amdgcn_s_sleep(2);
        }
        __threadfence();
    }
    __syncthreads();
}

// LDS layout (byte offsets into shbuf), max phase = P1 = 24576 B
// P1: srows4@0(20480) gtb@20480 pbbS@21504 ancS@22528 labS@23040
//     maskS16@23296 hcnt@23808 hslot@24064 gbase@24320
// P2: cmerge@0 (512)
// P3: gtb@0(1024) labS@1024 mgS@1280 labL@1536 perL@2560

__global__ __launch_bounds__(256, 4) void k_tal(
    const float* __restrict__ pd_scores, const float* __restrict__ pd_bboxes,
    const float* __restrict__ anc, const int* __restrict__ gt_labels,
    const float* __restrict__ gt_bboxes, const float* __restrict__ mask_gt,
    int* __restrict__ bar, int* __restrict__ ccnt,
    int* __restrict__ cntb, int* __restrict__ mselb, float* __restrict__ aselb,
    u64* __restrict__ cand,
    float* __restrict__ out0, float* __restrict__ out1,
    float* __restrict__ out3, float* __restrict__ out4,
    floatx4* __restrict__ cls4)
{
    __shared__ __align__(16) char shbuf[24576];
    const int tid = threadIdx.x;

    // ================= Phase 1: align + emit (tiles of 64 anchors) ========
    {
        float4* srows4 = (float4*)shbuf;
        float4* gtb    = (float4*)(shbuf + 20480);
        float4* pbbS   = (float4*)(shbuf + 21504);
        float2* ancS   = (float2*)(shbuf + 22528);
        int*    labS   = (int*)   (shbuf + 23040);
        unsigned short* maskS16 = (unsigned short*)(shbuf + 23296);
        int*    hcnt   = (int*)(shbuf + 23808);
        int*    hslot  = (int*)(shbuf + 24064);
        int*    gbase  = (int*)(shbuf + 24320);

        const int a = tid >> 2;       // anchor 0..63
        const int q = tid & 3;        // gt-piece 0..3

        for (int t = blockIdx.x; t < NT1; t += NBLK) {
            const int b = t / 132;
            const int n0 = (t % 132) * 64;
            __syncthreads();          // LDS reuse across tile iterations

            // issue dense score stage loads FIRST (fly across pass A)
            const float4* src4 = (const float4*)(pd_scores + (size_t)b * NN * CC);
            const int base4 = n0 * 20;
            const int lim = NN * 20 - base4;
            float4 r0 = (tid        < lim) ? src4[base4 + tid       ] : make_float4(0,0,0,0);
            float4 r1 = (tid + 256  < lim) ? src4[base4 + tid + 256 ] : make_float4(0,0,0,0);
            float4 r2 = (tid + 512  < lim) ? src4[base4 + tid + 512 ] : make_float4(0,0,0,0);
            float4 r3 = (tid + 768  < lim) ? src4[base4 + tid + 768 ] : make_float4(0,0,0,0);
            float4 r4 = (tid + 1024 < lim) ? src4[base4 + tid + 1024] : make_float4(0,0,0,0);

            if (tid < MM) {
                float4 g = *(const float4*)&gt_bboxes[(size_t)(b * MM + tid) * 4];
                if (mask_gt[b * MM + tid] <= 0.5f)
                    g = make_float4(1e30f, 1e30f, -1e30f, -1e30f);  // never hit
                gtb[tid] = g;
                int lb = gt_labels[b * MM + tid];
                labS[tid] = lb > 0 ? lb : 0;
                hcnt[tid] = 0;
                hslot[tid] = 0;
            }
            if (tid < 64) {
                int gn = n0 + tid;
                pbbS[tid] = (gn < NN)
                    ? *(const float4*)&pd_bboxes[((size_t)b * NN + gn) * 4]
                    : make_float4(0.f, 0.f, 0.f, 0.f);
                ancS[tid] = (gn < NN) ? *(const float2*)&anc[2 * gn]
                                      : make_float2(0.f, 0.f);
            }
            __syncthreads();

            // pass A: in-box u16 piece (atomic-light), overlaps score loads
            {
                unsigned short pm = 0;
                if (n0 + a < NN) {
                    float ax = ancS[a].x, ay = ancS[a].y;
                    #pragma unroll
                    for (int mm = 0; mm < 16; ++mm) {
                        float4 g = gtb[q * 16 + mm];
                        float d1 = ax - g.x, d2 = ay - g.y;
                        float d3 = g.z - ax, d4 = g.w - ay;
                        if (fminf(fminf(d1, d2), fminf(d3, d4)) > FEPS)
                            pm |= (unsigned short)(1u << mm);
                    }
                }
                maskS16[tid] = pm;
                unsigned t16 = pm;
                while (t16) {
                    int mm = __ffs(t16) - 1; t16 &= t16 - 1;
                    atomicAdd(&hcnt[q * 16 + mm], 1);
                }
            }
            // commit staged scores to LDS (vmcnt wait lands here)
            srows4[tid       ] = r0;
            srows4[tid + 256 ] = r1;
            srows4[tid + 512 ] = r2;
            srows4[tid + 768 ] = r3;
            srows4[tid + 1024] = r4;
            __syncthreads();

            if (tid < MM && hcnt[tid] > 0)
                gbase[tid] = atomicAdd(&ccnt[b * MM + tid], hcnt[tid]);
            __syncthreads();

            // emission: thread (a,q) walks its piece, computes align from LDS
            {
                unsigned t16 = maskS16[tid];
                if (t16) {
                    const float4 p = pbbS[a];
                    const float* row = (const float*)srows4 + a * 80;
                    const int gn = n0 + a;
                    while (t16) {
                        int mm = __ffs(t16) - 1; t16 &= t16 - 1;
                        int m = q * 16 + mm;
                        float io = iou_pair(gtb[m], p);
                        float x = row[labS[m]];
                        float s = 1.0f / (1.0f + expf(-x));
                        float i2 = io * io;
                        unsigned key = __float_as_uint(s * (i2 * i2 * i2)); // >=0
                        int slot = gbase[m] + atomicAdd(&hslot[m], 1);
                        if (slot < CAP)
                            st_dev_u64(&cand[(size_t)(b * MM + m) * CAP + slot],
                                       ((u64)key << 32) | (unsigned)(NN - gn));
                    }
                }
            }
        }
    }
    grid_barrier(bar);

    // ================= Phase 2: per-(b,m) top-13 ==========================
    {
        u64* cmerge = (u64*)shbuf;
        const int bm = blockIdx.x;           // exactly 1024
        const int b = bm >> 6, m = bm & 63;
        const int lane = tid & 63;
        const int wid = tid >> 6;
        const unsigned epskey = __float_as_uint(FEPS);
        const int count = min(ld_dev_i32(&ccnt[bm]), CAP);
        const u64* list = cand + (size_t)bm * CAP;

        u64 e[RPW];
        #pragma unroll
        for (int j = 0; j < RPW; ++j) {
            int i = tid + j * 256;
            e[j] = (i < count) ? ld_dev_u64(&list[i]) : 0ull;   // coalesced
        }

        // stage A: per-wave top-13 of its subset, in registers
        {
            u64 lm = 0ull;
            #pragma unroll
            for (int j = 0; j < RPW; ++j) if (e[j] > lm) lm = e[j];

            u64 winv = 0ull;
            for (int r = 0; r < KTOP; ++r) {
                u64 bv = lm;
                #pragma unroll
                for (int off = 32; off > 0; off >>= 1) {
                    u64 ov = __shfl_xor(bv, off, 64);
                    if (ov > bv) bv = ov;
                }
                if ((unsigned)(bv >> 32) <= epskey) break;
                if (lane == r) winv = bv;
                if (lm == bv) {                 // unique -> exactly one lane
                    #pragma unroll
                    for (int j = 0; j < RPW; ++j) if (e[j] == bv) e[j] = 0ull;
                    lm = 0ull;
                    #pragma unroll
                    for (int j = 0; j < RPW; ++j) if (e[j] > lm) lm = e[j];
                }
            }
            if (lane < KTOP) cmerge[wid * KTOP + lane] = winv;
            if (wid == 0 && lane >= 4 * KTOP) cmerge[lane] = 0ull;  // pad
        }
        __syncthreads();

        // stage B: wave 0 merges 52 candidates -> top-13, emits positives
        if (wid == 0) {
            u64 v = cmerge[lane];
            u64 winv = 0ull;
            for (int r = 0; r < KTOP; ++r) {
                u64 bv = v;
                #pragma unroll
                for (int off = 32; off > 0; off >>= 1) {
                    u64 ov = __shfl_xor(bv, off, 64);
                    if (ov > bv) bv = ov;
                }
                if ((unsigned)(bv >> 32) <= epskey) break;
                if (lane == r) winv = bv;
                if (v == bv) v = 0ull;
            }
            if (lane < KTOP) {
                unsigned hk = (unsigned)(winv >> 32);
                if (hk > epskey) {   // positive floats: uint order == float order
                    int n = NN - (int)(winv & 0xFFFFFFFFull);
                    int ai = b * NN + n;
                    atomicAdd(&cntb[ai], 1);
                    atomicAdd(&mselb[ai], m);
                    atomicAdd(&aselb[ai], __uint_as_float(hk));
                }
            }
        }
    }
    grid_barrier(bar);

    // ================= Phase 3: assign + cls ==============================
    if (blockIdx.x < NT3) {
        float4* gtb  = (float4*)shbuf;
        int*    labS = (int*)  (shbuf + 1024);
        float*  mgS  = (float*)(shbuf + 1280);
        int*    labL = (int*)  (shbuf + 1536);
        float*  perL = (float*)(shbuf + 2560);

        const int b = blockIdx.x / 33;
        const int n0 = (blockIdx.x % 33) * 256;
        const int n = n0 + tid;

        if (tid < MM) {
            int m = tid;
            gtb[m]  = *(const float4*)&gt_bboxes[(size_t)(b * MM + m) * 4];
            labS[m] = gt_labels[b * MM + m];
            mgS[m]  = mask_gt[b * MM + m];
        }
        __syncthreads();

        float per = 0.0f, fg = 0.0f;
        int mstar = 0;

        if (n < NN) {
            const size_t idx = (size_t)b * NN + n;
            const int cnt = ld_dev_i32(&cntb[idx]);
            if (cnt > 0) {
                fg = 1.0f;
                const float4 p = *(const float4*)&pd_bboxes[idx * 4];
                if (cnt == 1) {
                    mstar = ld_dev_i32(&mselb[idx]);
                    float a = ld_dev_f32(&aselb[idx]);
                    float io = iou_pair(gtb[mstar], p);   // positive => valid
                    per = a / (a + FEPS) * io;
                } else {
                    // multi-assigned: argmax IoU over valid m (first-max wins)
                    float2 a2 = *(const float2*)&anc[2 * n];
                    float bestI = -1.0f; int bestM = 0;
                    for (int m = 0; m < MM; ++m) {
                        float4 gg = gtb[m];
                        float d1 = a2.x - gg.x, d2 = a2.y - gg.y;
                        float d3 = gg.z - a2.x, d4 = gg.w - a2.y;
                        bool valid = (fminf(fminf(d1, d2), fminf(d3, d4)) > FEPS)
                                     && (mgS[m] > 0.5f);
                        float io = valid ? iou_pair(gg, p) : 0.0f;
                        if (io > bestI) { bestI = io; bestM = m; }
                    }
                    mstar = bestM;
                    float io = bestI;
                    int lb = labS[mstar]; int lbc = lb > 0 ? lb : 0;
                    float x = pd_scores[idx * CC + lbc];
                    float s = 1.0f / (1.0f + expf(-x));
                    float i2 = io * io;
                    float a = s * (i2 * i2 * i2);   // continuous-only recompute
                    per = a / (a + FEPS) * io;
                }
            }
            out0[idx] = (float)labS[mstar];
            ((float4*)out1)[idx] = gtb[mstar];
            out3[idx] = fg;
            out4[idx] = (float)mstar;
        }
        labL[tid] = (n < NN) ? labS[mstar] : 0;
        perL[tid] = per;
        __syncthreads();

        // cls rows for this tile's 256 anchors: 5120 float4s, coalesced
        const size_t base4 = ((size_t)b * NN + n0) * 20;
        for (int k = tid; k < 5120; k += 256) {
            int lrow = k / 20;
            int gn = n0 + lrow;
            if (gn >= NN) break;
            int c4 = (k - lrow * 20) * 4;
            int lab = labL[lrow];
            float pr = perL[lrow];
            int d = lab - c4;
            floatx4 v;
            v.x = (d == 0) ? pr : 0.0f;
            v.y = (d == 1) ? pr : 0.0f;
            v.z = (d == 2) ? pr : 0.0f;
            v.w = (d == 3) ? pr : 0.0f;
            __builtin_nontemporal_store(v, &cls4[base4 + k]);
        }
    }
}

extern "C" void kernel_launch(void* const* d_in, const int* in_sizes, int n_in,
                              void* d_out, int out_size, void* d_ws, size_t ws_size,
                              hipStream_t stream) {
    const float* pd_scores = (const float*)d_in[0];
    const float* pd_bboxes = (const float*)d_in[1];
    const float* anc       = (const float*)d_in[2];
    const int*   gt_labels = (const int*)d_in[3];
    const float* gt_bboxes = (const float*)d_in[4];
    const float* mask_gt   = (const float*)d_in[5];

    float* out  = (float*)d_out;
    float* out0 = out;
    float* out1 = out + OFF_O1;
    float* out2 = out + OFF_O2;
    float* out3 = out + OFF_O3;
    float* out4 = out + OFF_O4;

    int*   ws_i  = (int*)d_ws;
    int*   bar   = ws_i;                                  // 2
    int*   ccnt  = ws_i + 2;                              // 1024
    int*   cntb  = ws_i + 2 + 1024;                       // 134400
    int*   mselb = ws_i + 2 + 1024 + 134400;              // 134400
    float* aselb = (float*)(ws_i + 2 + 1024 + 2 * 134400);// 134400
    u64*   cand  = (u64*)((char*)d_ws + (size_t)ZERO_INTS * 4);  // 16MB

    // zero barrier + atomic scratch (graph-capturable async memset)
    hipMemsetAsync(d_ws, 0, (size_t)ZERO_INTS * 4, stream);

    k_tal<<<dim3(NBLK), dim3(256), 0, stream>>>(
        pd_scores, pd_bboxes, anc, gt_labels, gt_bboxes, mask_gt,
        bar, ccnt, cntb, mselb, aselb, cand,
        out0, out1, out3, out4, (floatx4*)out2);
}

// Round 14
// 82.518 us; speedup vs baseline: 4.1381x; 4.1381x over previous
//
#include <hip/hip_runtime.h>
#include <math.h>

#define BB 16
#define NN 8400
#define CC 80
#define MM 64
#define KTOP 13
#define FEPS 1e-9f
#define CAP 2048   // per-(b,m) candidate capacity; theoretical max 1344
#define RPW 8      // u64 regs/lane for selection: RPW*256 == CAP

typedef float floatx4 __attribute__((ext_vector_type(4)));
typedef unsigned long long u64;

// ---- output layout (floats) ----
#define OFF_O1 134400
#define OFF_O2 672000
#define OFF_O3 11424000
#define OFF_O4 11558400

// ---- d_ws layout ----
// ccnt[1024 i32] | poscnt[16 i32]            (memset-zeroed, 4160 B)
// poslist[16*1024 u64]  at byte 4160
// cand[1024*2048 u64]   at byte 135232
#define POSL_OFF 4160
#define CAND_OFF 135232
#define ZERO_BYTES 4160

__device__ __forceinline__ float iou_pair(const float4 g, const float4 p) {
    float ix1 = fmaxf(g.x, p.x);
    float iy1 = fmaxf(g.y, p.y);
    float ix2 = fminf(g.z, p.z);
    float iy2 = fminf(g.w, p.w);
    float iw = fmaxf(ix2 - ix1, 0.0f);
    float ih = fmaxf(iy2 - iy1, 0.0f);
    float inter = iw * ih;
    float aa = (g.z - g.x) * (g.w - g.y);
    float ab = (p.z - p.x) * (p.w - p.y);
    float uni = fmaxf(aa + ab - inter, FEPS);
    return inter / uni;
}

// K1': tiles of 64 anchors. (a) prefetch-staged dense score rows -> LDS,
// (b) in-box masks, (c) emit u64 composites (key<<32)|(NN-n) to per-(b,m)
// lists, (d) bulk DEFAULT output writes for this tile (backgrounds),
// overlapped with compute. Positives fixed up later by k_resolve.
__global__ __launch_bounds__(256) void k_align_emit(
    const float* __restrict__ pd_scores, const float* __restrict__ pd_bboxes,
    const float* __restrict__ anc, const int* __restrict__ gt_labels,
    const float* __restrict__ gt_bboxes, const float* __restrict__ mask_gt,
    int* __restrict__ ccnt, u64* __restrict__ cand,
    float* __restrict__ out0, float* __restrict__ out1,
    float* __restrict__ out3, float* __restrict__ out4,
    floatx4* __restrict__ cls4)
{
    const int b = blockIdx.y;
    const int n0 = blockIdx.x * 64;
    const int tid = threadIdx.x;
    const int a = tid >> 2;       // anchor 0..63
    const int q = tid & 3;        // gt-piece 0..3

    __shared__ float4 srows4[1280];        // 64 rows x 20 float4 = 20 KB
    __shared__ float4 gtb[MM];
    __shared__ float4 pbbS[64];
    __shared__ float2 ancS[64];
    __shared__ int    labS[MM];
    __shared__ unsigned short maskS16[256];
    __shared__ int hcnt[MM], hslot[MM], gbase[MM];

    // issue dense score stage loads FIRST (fly across pass A)
    const float4* src4 = (const float4*)(pd_scores + (size_t)b * NN * CC);
    const int base4 = n0 * 20;
    const int lim = NN * 20 - base4;
    float4 r0 = (tid        < lim) ? src4[base4 + tid       ] : make_float4(0,0,0,0);
    float4 r1 = (tid + 256  < lim) ? src4[base4 + tid + 256 ] : make_float4(0,0,0,0);
    float4 r2 = (tid + 512  < lim) ? src4[base4 + tid + 512 ] : make_float4(0,0,0,0);
    float4 r3 = (tid + 768  < lim) ? src4[base4 + tid + 768 ] : make_float4(0,0,0,0);
    float4 r4 = (tid + 1024 < lim) ? src4[base4 + tid + 1024] : make_float4(0,0,0,0);

    if (tid < MM) {
        float4 g = *(const float4*)&gt_bboxes[(size_t)(b * MM + tid) * 4];
        if (mask_gt[b * MM + tid] <= 0.5f)
            g = make_float4(1e30f, 1e30f, -1e30f, -1e30f);  // never hit
        gtb[tid] = g;
        int lb = gt_labels[b * MM + tid];
        labS[tid] = lb > 0 ? lb : 0;
        hcnt[tid] = 0;
        hslot[tid] = 0;
    }
    if (tid < 64) {
        int gn = n0 + tid;
        pbbS[tid] = (gn < NN)
            ? *(const float4*)&pd_bboxes[((size_t)b * NN + gn) * 4]
            : make_float4(0.f, 0.f, 0.f, 0.f);
        ancS[tid] = (gn < NN) ? *(const float2*)&anc[2 * gn]
                              : make_float2(0.f, 0.f);
    }
    __syncthreads();

    // pass A: in-box u16 piece (atomic-light), overlaps score loads
    {
        unsigned short pm = 0;
        if (n0 + a < NN) {
            float ax = ancS[a].x, ay = ancS[a].y;
            #pragma unroll
            for (int mm = 0; mm < 16; ++mm) {
                float4 g = gtb[q * 16 + mm];
                float d1 = ax - g.x, d2 = ay - g.y;
                float d3 = g.z - ax, d4 = g.w - ay;
                if (fminf(fminf(d1, d2), fminf(d3, d4)) > FEPS)
                    pm |= (unsigned short)(1u << mm);
            }
        }
        maskS16[tid] = pm;
        unsigned t16 = pm;
        while (t16) {
            int mm = __ffs(t16) - 1; t16 &= t16 - 1;
            atomicAdd(&hcnt[q * 16 + mm], 1);
        }
    }
    // commit staged scores to LDS (vmcnt wait lands here)
    srows4[tid       ] = r0;
    srows4[tid + 256 ] = r1;
    srows4[tid + 512 ] = r2;
    srows4[tid + 768 ] = r3;
    srows4[tid + 1024] = r4;
    __syncthreads();

    if (tid < MM && hcnt[tid] > 0)
        gbase[tid] = atomicAdd(&ccnt[b * MM + tid], hcnt[tid]);
    __syncthreads();

    // emission: thread (a,q) walks its piece, computes align from LDS
    {
        unsigned t16 = maskS16[tid];
        if (t16) {
            const float4 p = pbbS[a];
            const float* row = (const float*)srows4 + a * 80;
            const int gn = n0 + a;
            while (t16) {
                int mm = __ffs(t16) - 1; t16 &= t16 - 1;
                int m = q * 16 + mm;
                float io = iou_pair(gtb[m], p);
                float x = row[labS[m]];
                float s = 1.0f / (1.0f + expf(-x));
                float i2 = io * io;
                unsigned key = __float_as_uint(s * (i2 * i2 * i2));  // >= 0
                int slot = gbase[m] + atomicAdd(&hslot[m], 1);
                if (slot < CAP)
                    cand[(size_t)(b * MM + m) * CAP + slot] =
                        ((u64)key << 32) | (unsigned)(NN - gn);
            }
        }
    }

    // bulk DEFAULT output writes for this tile (positives fixed up later)
    {
        const float lab0 = (float)gt_labels[b * MM];               // raw
        const float4 g0 = *(const float4*)&gt_bboxes[(size_t)b * MM * 4]; // raw
        const floatx4 z = {0.f, 0.f, 0.f, 0.f};
        const size_t cbase4 = ((size_t)b * NN + n0) * 20;
        for (int k = tid; k < 1280; k += 256) {
            int gn = n0 + k / 20;
            if (gn < NN) __builtin_nontemporal_store(z, &cls4[cbase4 + k]);
        }
        if (tid < 64) {
            int gn = n0 + tid;
            if (gn < NN) {
                size_t idx = (size_t)b * NN + gn;
                out0[idx] = lab0;
                ((float4*)out1)[idx] = g0;
                out3[idx] = 0.0f;
                out4[idx] = 0.0f;
            }
        }
    }
}

// K2a: one workgroup per (b,m). Coalesced u64 candidate reads into registers,
// hierarchical 4-wave top-13 over unique composites, merge, emit winners to
// the per-batch compact poslist: entry = key<<20 | n<<6 | m.
__global__ __launch_bounds__(256) void k_topk(
    const int* __restrict__ ccnt, const u64* __restrict__ cand,
    int* __restrict__ poscnt, u64* __restrict__ poslist)
{
    const int bm = blockIdx.x;
    const int b = bm >> 6, m = bm & 63;
    const int tid = threadIdx.x;
    const int lane = tid & 63;
    const int wid = tid >> 6;

    __shared__ u64 cmerge[64];

    const unsigned epskey = __float_as_uint(FEPS);
    const int count = min(ccnt[bm], CAP);
    const u64* list = cand + (size_t)bm * CAP;

    u64 e[RPW];
    #pragma unroll
    for (int j = 0; j < RPW; ++j) {
        int i = tid + j * 256;
        e[j] = (i < count) ? list[i] : 0ull;   // coalesced
    }

    // stage A: per-wave top-13 of its subset, in registers
    {
        u64 lm = 0ull;
        #pragma unroll
        for (int j = 0; j < RPW; ++j) if (e[j] > lm) lm = e[j];

        u64 winv = 0ull;
        for (int r = 0; r < KTOP; ++r) {
            u64 bv = lm;
            #pragma unroll
            for (int off = 32; off > 0; off >>= 1) {
                u64 ov = __shfl_xor(bv, off, 64);
                if (ov > bv) bv = ov;
            }
            if ((unsigned)(bv >> 32) <= epskey) break;
            if (lane == r) winv = bv;
            if (lm == bv) {                    // unique -> exactly one lane
                #pragma unroll
                for (int j = 0; j < RPW; ++j) if (e[j] == bv) e[j] = 0ull;
                lm = 0ull;
                #pragma unroll
                for (int j = 0; j < RPW; ++j) if (e[j] > lm) lm = e[j];
            }
        }
        if (lane < KTOP) cmerge[wid * KTOP + lane] = winv;
        if (wid == 0 && lane >= 4 * KTOP) cmerge[lane] = 0ull;  // pad 52..63
    }
    __syncthreads();

    // stage B: wave 0 merges 52 candidates -> global top-13, emits
    if (wid == 0) {
        u64 v = cmerge[lane];
        u64 winv = 0ull;
        for (int r = 0; r < KTOP; ++r) {
            u64 bv = v;
            #pragma unroll
            for (int off = 32; off > 0; off >>= 1) {
                u64 ov = __shfl_xor(bv, off, 64);
                if (ov > bv) bv = ov;
            }
            if ((unsigned)(bv >> 32) <= epskey) break;
            if (lane == r) winv = bv;
            if (v == bv) v = 0ull;
        }
        if (lane < KTOP) {
            unsigned hk = (unsigned)(winv >> 32);
            if (hk > epskey) {     // positive floats: uint order == float order
                int n = NN - (int)(winv & 0xFFFFFFFFull);
                int pos = atomicAdd(&poscnt[b], 1);
                if (pos < 1024)
                    poslist[(size_t)b * 1024 + pos] =
                        ((u64)hk << 20) | ((u64)n << 6) | (u64)m;
            }
        }
    }
}

// K2b: one block per batch. Count positives per anchor in LDS, then fix up
// only positive anchors (cnt==1 direct; cnt>1 argmax-IoU with claim bit).
__global__ __launch_bounds__(256) void k_resolve(
    const int* __restrict__ poscnt, const u64* __restrict__ poslist,
    const float* __restrict__ pd_scores, const float* __restrict__ pd_bboxes,
    const float* __restrict__ anc, const int* __restrict__ gt_labels,
    const float* __restrict__ gt_bboxes, const float* __restrict__ mask_gt,
    float* __restrict__ out0, float* __restrict__ out1,
    float* __restrict__ out3, float* __restrict__ out4,
    float* __restrict__ cls)
{
    const int b = blockIdx.x;
    const int tid = threadIdx.x;

    __shared__ unsigned cntL[NN];      // 33.6 KB: low16 = count, bit31 = claim
    __shared__ float4 gtbR[MM];        // raw boxes
    __shared__ int    labR[MM];        // raw labels
    __shared__ float  mgR[MM];

    for (int i = tid; i < NN; i += 256) cntL[i] = 0u;
    if (tid < MM) {
        gtbR[tid] = *(const float4*)&gt_bboxes[(size_t)(b * MM + tid) * 4];
        labR[tid] = gt_labels[b * MM + tid];
        mgR[tid]  = mask_gt[b * MM + tid];
    }
    __syncthreads();

    const int np = min(poscnt[b], 1024);
    const u64* list = poslist + (size_t)b * 1024;

    for (int i = tid; i < np; i += 256) {
        int n = (int)((list[i] >> 6) & 0x3FFF);
        atomicAdd(&cntL[n], 1u);
    }
    __syncthreads();

    for (int i = tid; i < np; i += 256) {
        const u64 e = list[i];
        const unsigned hk = (unsigned)(e >> 20);
        const int n = (int)((e >> 6) & 0x3FFF);
        const int m = (int)(e & 63);
        const size_t idx = (size_t)b * NN + n;
        const unsigned c = cntL[n] & 0xFFFFu;

        int mstar; float per;
        const float4 p = *(const float4*)&pd_bboxes[idx * 4];
        if (c == 1) {
            mstar = m;
            float a = __uint_as_float(hk);
            float io = iou_pair(gtbR[mstar], p);   // positive => valid
            per = a / (a + FEPS) * io;
        } else {
            // claim: exactly one entry per anchor processes (deterministic
            // result — computation depends only on (b,n))
            unsigned old = atomicOr(&cntL[n], 0x80000000u);
            if (old & 0x80000000u) continue;
            float2 a2 = *(const float2*)&anc[2 * n];
            float bestI = -1.0f; int bestM = 0;
            for (int m2 = 0; m2 < MM; ++m2) {
                float4 gg = gtbR[m2];
                float d1 = a2.x - gg.x, d2 = a2.y - gg.y;
                float d3 = gg.z - a2.x, d4 = gg.w - a2.y;
                bool valid = (fminf(fminf(d1, d2), fminf(d3, d4)) > FEPS) &&
                             (mgR[m2] > 0.5f);
                float io = valid ? iou_pair(gg, p) : 0.0f;
                if (io > bestI) { bestI = io; bestM = m2; }   // first-max wins
            }
            mstar = bestM;
            float io = bestI;
            int lb = labR[mstar]; int lbc = lb > 0 ? lb : 0;
            float x = pd_scores[idx * CC + lbc];
            float s = 1.0f / (1.0f + expf(-x));
            float i2 = io * io;
            float a = s * (i2 * i2 * i2);      // continuous-only recompute
            per = a / (a + FEPS) * io;
        }

        out0[idx] = (float)labR[mstar];
        ((float4*)out1)[idx] = gtbR[mstar];
        out3[idx] = 1.0f;
        out4[idx] = (float)mstar;
        int lab = labR[mstar];
        if (lab >= 0 && lab < CC) cls[idx * CC + lab] = per;
    }
}

extern "C" void kernel_launch(void* const* d_in, const int* in_sizes, int n_in,
                              void* d_out, int out_size, void* d_ws, size_t ws_size,
                              hipStream_t stream) {
    const float* pd_scores = (const float*)d_in[0];
    const float* pd_bboxes = (const float*)d_in[1];
    const float* anc       = (const float*)d_in[2];
    const int*   gt_labels = (const int*)d_in[3];
    const float* gt_bboxes = (const float*)d_in[4];
    const float* mask_gt   = (const float*)d_in[5];

    float* out  = (float*)d_out;
    float* out0 = out;
    float* out1 = out + OFF_O1;
    float* out2 = out + OFF_O2;
    float* out3 = out + OFF_O3;
    float* out4 = out + OFF_O4;

    int*   ccnt    = (int*)d_ws;                               // 1024
    int*   poscnt  = (int*)d_ws + 1024;                        // 16
    u64*   poslist = (u64*)((char*)d_ws + POSL_OFF);           // 16*1024
    u64*   cand    = (u64*)((char*)d_ws + CAND_OFF);           // 16MB

    // 0) zero the tiny atomic counters
    hipMemsetAsync(d_ws, 0, ZERO_BYTES, stream);

    // 1) align+emit + bulk default outputs (overlapped streaming writes)
    k_align_emit<<<dim3((NN + 63) / 64, BB), dim3(256), 0, stream>>>(
        pd_scores, pd_bboxes, anc, gt_labels, gt_bboxes, mask_gt,
        ccnt, cand, out0, out1, out3, out4, (floatx4*)out2);

    // 2) per-(b,m) register top-13 -> compact per-batch positive list
    k_topk<<<dim3(BB * MM), dim3(256), 0, stream>>>(
        ccnt, cand, poscnt, poslist);

    // 3) per-batch resolve + positive fixups (tiny)
    k_resolve<<<dim3(BB), dim3(256), 0, stream>>>(
        poscnt, poslist, pd_scores, pd_bboxes, anc, gt_labels, gt_bboxes,
        mask_gt, out0, out1, out3, out4, out2);
}